// Round 6
// baseline (3673.017 us; speedup 1.0000x reference)
//
#include <hip/hip_runtime.h>

// resFAN round 6: software-pipelined (double-buffered LDS) K-loops for
// rf_mconv and rf_vgemmm.  Prefetch DMA for iter i+1 issued after the
// top-of-loop barrier -> in flight during iter i's MFMA phase; one barrier
// per iteration.  Halo/OOB lanes now read a zero page via per-lane DMA
// source addresses (no LDS pre-zeroing).  Everything else = round 5 (passed).

#define NPIX 4096

typedef _Float16 f16;
typedef _Float16 f16x8 __attribute__((ext_vector_type(8)));
typedef _Float16 f16x4 __attribute__((ext_vector_type(4)));
typedef float f32x4 __attribute__((ext_vector_type(4)));

__device__ inline void async16(const void* g, void* l) {
  __builtin_amdgcn_global_load_lds(
      (const __attribute__((address_space(1))) unsigned int*)g,
      (__attribute__((address_space(3))) unsigned int*)l, 16, 0, 0);
}

// ---------------- small prep kernels ----------------

__global__ void rf_zero(float* __restrict__ z) { z[threadIdx.x] = 0.f; }

__global__ void rf_s(const float* __restrict__ wB, const float* __restrict__ bA,
                     float* __restrict__ s_out, float* __restrict__ c0_out) {
  int c = threadIdx.x;  // 128 threads
  const float* row = wB + (size_t)c * 1024;
  float acc = 0.f;
  for (int i = 0; i < 1024; ++i) acc += row[i];
  s_out[c] = acc;
  __shared__ float sh[128];
  sh[c] = acc * bA[c];
  __syncthreads();
  for (int off = 64; off > 0; off >>= 1) {
    if (c < off) sh[c] += sh[c + off];
    __syncthreads();
  }
  if (c == 0) c0_out[0] = sh[0];
}

__global__ void rf_u(const float* __restrict__ wA, const float* __restrict__ s,
                     float* __restrict__ u) {
  int i = blockIdx.x * 256 + threadIdx.x;  // 1024 total
  float acc = 0.f;
  for (int c = 0; c < 128; ++c) acc += s[c] * wA[(size_t)c * 1024 + i];
  u[i] = acc;
}

__global__ void rf_fstat(const float* __restrict__ in, float* __restrict__ fstat) {
  int b = blockIdx.x;
  int t = threadIdx.x;
  const float* f = in + ((size_t)b * 1025 + 1024) * NPIX;
  float mx = -1e30f, mn = 1e30f;
  for (int j = t; j < NPIX; j += 256) {
    float v = f[j];
    mx = fmaxf(mx, v);
    mn = fminf(mn, v);
  }
  __shared__ float smx[256], smn[256];
  smx[t] = mx; smn[t] = mn;
  __syncthreads();
  for (int off = 128; off > 0; off >>= 1) {
    if (t < off) {
      smx[t] = fmaxf(smx[t], smx[t + off]);
      smn[t] = fminf(smn[t], smn[t + off]);
    }
    __syncthreads();
  }
  if (t == 0) { fstat[b] = smx[0]; fstat[4 + b] = smn[0]; }
}

__global__ __launch_bounds__(256) void rf_A(const float* __restrict__ in,
                                            const float* __restrict__ u,
                                            const float* __restrict__ c0p,
                                            const float* __restrict__ fst,
                                            float* __restrict__ A, float* __restrict__ M) {
  __shared__ float ul[1024];
  int b = blockIdx.y;
  int n = blockIdx.x * 256 + threadIdx.x;
  for (int s = threadIdx.x; s < 1024; s += 256) ul[s] = u[s];
  __syncthreads();
  const float* xp = in + (size_t)b * 1025 * NPIX + n;
  float acc = c0p[0];
#pragma unroll 8
  for (int i = 0; i < 1024; ++i) acc = fmaf(ul[i], xp[(size_t)i * NPIX], acc);
  A[b * NPIX + n] = acc;
  M[b * NPIX + n] = fmaxf(acc * fst[b], acc * fst[4 + b]);
}

__global__ void rf_Z(const float* __restrict__ in, const float* __restrict__ A,
                     const float* __restrict__ M, float* __restrict__ iZ) {
  int idx = blockIdx.x * 4 + (threadIdx.x >> 6);  // (b,n) pair, 16384 total
  int lane = threadIdx.x & 63;
  int b = idx >> 12;
  const float* f = in + ((size_t)b * 1025 + 1024) * NPIX;
  float a = A[idx], m = M[idx];
  float acc = 0.f;
#pragma unroll 4
  for (int it = 0; it < 64; ++it) acc += __expf(a * f[lane + it * 64] - m);
  for (int off = 32; off > 0; off >>= 1) acc += __shfl_down(acc, off, 64);
  if (lane == 0) iZ[idx] = 1.0f / acc;
}

// ---------------- x transpose: [b][ci][n] f32 -> [b][n][ci] f16, scale 16 ---

__global__ void rf_xsplit(const float* __restrict__ in, f16* __restrict__ xh) {
  __shared__ float tl[64][65];
  int nt = blockIdx.x, ct = blockIdx.y, b = blockIdx.z;
  int n0 = nt * 64, c0 = ct * 64;
  int tid = threadIdx.x;
  for (int s = tid; s < 4096; s += 256) {
    int r = s >> 6, c = s & 63;
    tl[r][c] = in[((size_t)b * 1025 + c0 + r) * NPIX + n0 + c];
  }
  __syncthreads();
  for (int s = tid; s < 512; s += 256) {
    int n = s >> 3, g = s & 7;
    f16x8 hb;
#pragma unroll
    for (int q = 0; q < 8; ++q) hb[q] = (f16)(16.f * tl[g * 8 + q][n]);
    size_t o = ((size_t)b * NPIX + n0 + n) * 1024 + c0 + g * 8;
    *(f16x8*)&xh[o] = hb;
  }
}

// ---------------- wC split: [1024][1024] f32 -> f16 pair, scale 256 --------

__global__ void rf_wCsplit(const float* __restrict__ wC, f16* __restrict__ wh,
                           f16* __restrict__ wl) {
  int base = (blockIdx.x * 256 + threadIdx.x) * 8;
  f16x8 hb, lb;
#pragma unroll
  for (int q = 0; q < 8; ++q) {
    float v = 256.f * wC[base + q];
    f16 h = (f16)v;
    hb[q] = h; lb[q] = (f16)(v - (float)h);
  }
  *(f16x8*)&wh[base] = hb;
  *(f16x8*)&wl[base] = lb;
}

// ---------------- MFMA v-GEMM (double-buffered): v = wC @ x + bC ----------

__global__ __launch_bounds__(256, 2) void rf_vgemmm(
    const f16* __restrict__ wh, const f16* __restrict__ wl,
    const f16* __restrict__ xh,
    const float* __restrict__ bC, f16* __restrict__ vH, f16* __restrict__ vL) {
  __shared__ f16 sAh[2][4096], sAl[2][4096], sBh[2][4096];
  const int tid = threadIdx.x;
  const int nb = blockIdx.x * 128, cb = blockIdx.y * 128, b = blockIdx.z;
  const int pA = tid & 127;
  const int wv = tid >> 6, lane = tid & 63;
  const int mrow = lane & 15, quad = lane >> 4;
  const int wm = (wv & 1) * 64, wn = (wv >> 1) * 64;
  const size_t abase = (size_t)(cb + pA) * 1024;
  const size_t bbase = ((size_t)b * NPIX + nb + pA) * 1024;
  f32x4 acc[4][4];
#pragma unroll
  for (int i = 0; i < 4; ++i)
#pragma unroll
    for (int j = 0; j < 4; ++j) acc[i][j] = (f32x4){0.f, 0.f, 0.f, 0.f};

  auto stage = [&](int k0, int pb) {
#pragma unroll
    for (int s = 0; s < 2; ++s) {
      const int cc = ((tid + 256 * s) >> 7) & 3;
      const int lb = ((tid & ~63) + 256 * s) * 8;
      size_t ga = abase + k0 + cc * 8;
      size_t gb = bbase + k0 + cc * 8;
      async16(wh + ga, &sAh[pb][lb]);
      async16(wl + ga, &sAl[pb][lb]);
      async16(xh + gb, &sBh[pb][lb]);
    }
  };
  stage(0, 0);
  int p = 0;
  for (int k0 = 0; k0 < 1024; k0 += 32) {
    __syncthreads();
    if (k0 + 32 < 1024) stage(k0 + 32, p ^ 1);
    f16x8 fah[4], fal[4], fbh[4];
#pragma unroll
    for (int mi = 0; mi < 4; ++mi) {
      int ix = (quad * 128 + wm + mi * 16 + mrow) * 8;
      fah[mi] = *(const f16x8*)&sAh[p][ix];
      fal[mi] = *(const f16x8*)&sAl[p][ix];
    }
#pragma unroll
    for (int ni = 0; ni < 4; ++ni) {
      int ix = (quad * 128 + wn + ni * 16 + mrow) * 8;
      fbh[ni] = *(const f16x8*)&sBh[p][ix];
    }
#pragma unroll
    for (int mi = 0; mi < 4; ++mi)
#pragma unroll
      for (int ni = 0; ni < 4; ++ni)
        acc[mi][ni] = __builtin_amdgcn_mfma_f32_16x16x32_f16(fah[mi], fbh[ni], acc[mi][ni], 0, 0, 0);
#pragma unroll
    for (int mi = 0; mi < 4; ++mi)
#pragma unroll
      for (int ni = 0; ni < 4; ++ni)
        acc[mi][ni] = __builtin_amdgcn_mfma_f32_16x16x32_f16(fal[mi], fbh[ni], acc[mi][ni], 0, 0, 0);
    p ^= 1;
  }
  const float inv = 1.0f / 4096.0f;
#pragma unroll
  for (int mi = 0; mi < 4; ++mi) {
#pragma unroll
    for (int rg = 0; rg < 4; ++rg) {
      int c = cb + wm + mi * 16 + quad * 4 + rg;
      float bv = bC[c];
#pragma unroll
      for (int ni = 0; ni < 4; ++ni) {
        int j = nb + wn + ni * 16 + mrow;
        float v = acc[mi][ni][rg] * inv + bv;
        float sv = 16.f * v;
        f16 h = (f16)sv;
        size_t o = ((size_t)b * 1024 + c) * NPIX + j;
        vH[o] = h;
        vL[o] = (f16)(sv - (float)h);
      }
    }
  }
}

// ---------------- MFMA attention out-GEMM + residual -> split y ------------

__global__ __launch_bounds__(256, 2) void rf_attm(
    const f16* __restrict__ vH, const f16* __restrict__ vL,
    const float* __restrict__ Aarr, const float* __restrict__ Marr,
    const float* __restrict__ iZ, const float* __restrict__ in,
    const float* __restrict__ gptr, f16* __restrict__ yH, f16* __restrict__ yL) {
  __shared__ f16 sAh[4096], sAl[4096], sPh[4096], sPl[4096];
  const int tid = threadIdx.x;
  const int ib = blockIdx.x * 128, cb = blockIdx.y * 128, b = blockIdx.z;
  const int pA = tid & 127;
  const int wv = tid >> 6, lane = tid & 63;
  const int mrow = lane & 15, quad = lane >> 4;
  const int wm = (wv & 1) * 64, wn = (wv >> 1) * 64;
  const size_t vbase = ((size_t)b * 1024 + cb + pA) * NPIX;
  const int ni_ = tid & 127;
  const int kc0 = tid >> 7;  // 0..1
  const float av = Aarr[b * NPIX + ib + ni_];
  const float mv = Marr[b * NPIX + ib + ni_];
  const float zv = iZ[b * NPIX + ib + ni_] * 16.f;
  const float* f = in + ((size_t)b * 1025 + 1024) * NPIX;
  f32x4 acc[4][4];
#pragma unroll
  for (int i = 0; i < 4; ++i)
#pragma unroll
    for (int j = 0; j < 4; ++j) acc[i][j] = (f32x4){0.f, 0.f, 0.f, 0.f};
  for (int j0 = 0; j0 < NPIX; j0 += 32) {
#pragma unroll
    for (int s = 0; s < 2; ++s) {
      const int cc = ((tid + 256 * s) >> 7) & 3;
      const int lb = ((tid & ~63) + 256 * s) * 8;
      size_t ga = vbase + j0 + cc * 8;
      async16(vH + ga, &sAh[lb]);
      async16(vL + ga, &sAl[lb]);
    }
#pragma unroll
    for (int it = 0; it < 2; ++it) {
      const int kc = kc0 + 2 * it;
      const float4 fa = *(const float4*)&f[j0 + kc * 8];
      const float4 fb = *(const float4*)&f[j0 + kc * 8 + 4];
      const float fj[8] = {fa.x, fa.y, fa.z, fa.w, fb.x, fb.y, fb.z, fb.w};
      f16x8 ph, plo;
#pragma unroll
      for (int q = 0; q < 8; ++q) {
        float p = __expf(fmaf(av, fj[q], -mv)) * zv;
        f16 h = (f16)p;
        ph[q] = h;
        plo[q] = (f16)(p - (float)h);
      }
      const int off = (kc * 128 + ni_) * 8;
      *(f16x8*)&sPh[off] = ph;
      *(f16x8*)&sPl[off] = plo;
    }
    __syncthreads();
    f16x8 fah[4], fal[4], fbh[4], fbl[4];
#pragma unroll
    for (int mi = 0; mi < 4; ++mi) {
      int ix = (quad * 128 + wm + mi * 16 + mrow) * 8;
      fah[mi] = *(const f16x8*)&sAh[ix];
      fal[mi] = *(const f16x8*)&sAl[ix];
    }
#pragma unroll
    for (int ni = 0; ni < 4; ++ni) {
      int ix = (quad * 128 + wn + ni * 16 + mrow) * 8;
      fbh[ni] = *(const f16x8*)&sPh[ix];
      fbl[ni] = *(const f16x8*)&sPl[ix];
    }
#pragma unroll
    for (int mi = 0; mi < 4; ++mi)
#pragma unroll
      for (int ni = 0; ni < 4; ++ni)
        acc[mi][ni] = __builtin_amdgcn_mfma_f32_16x16x32_f16(fah[mi], fbh[ni], acc[mi][ni], 0, 0, 0);
#pragma unroll
    for (int mi = 0; mi < 4; ++mi)
#pragma unroll
      for (int ni = 0; ni < 4; ++ni)
        acc[mi][ni] = __builtin_amdgcn_mfma_f32_16x16x32_f16(fah[mi], fbl[ni], acc[mi][ni], 0, 0, 0);
#pragma unroll
    for (int mi = 0; mi < 4; ++mi)
#pragma unroll
      for (int ni = 0; ni < 4; ++ni)
        acc[mi][ni] = __builtin_amdgcn_mfma_f32_16x16x32_f16(fal[mi], fbh[ni], acc[mi][ni], 0, 0, 0);
    __syncthreads();
  }
  const float g = gptr[0];
  const float inv = 1.0f / 256.0f;
#pragma unroll
  for (int mi = 0; mi < 4; ++mi) {
    const int cbase = cb + wm + mi * 16 + quad * 4;
#pragma unroll
    for (int ni = 0; ni < 4; ++ni) {
      const int i = ib + wn + ni * 16 + mrow;
      f16x4 hv, lv;
#pragma unroll
      for (int rg = 0; rg < 4; ++rg) {
        float xr = in[((size_t)b * 1025 + cbase + rg) * NPIX + i];
        float sv = 16.f * (g * (acc[mi][ni][rg] * inv) + xr);
        f16 h = (f16)sv;
        hv[rg] = h;
        lv[rg] = (f16)(sv - (float)h);
      }
      size_t o = ((size_t)b * NPIX + i) * 1024 + cbase;
      *(f16x4*)&yH[o] = hv;
      *(f16x4*)&yL[o] = lv;
    }
  }
}

// ---------------- weight split prep: [CO][CI][3][3] -> [9][CO][CI] hi/lo ----

__global__ void rf_wsplit(const float* __restrict__ w, f16* __restrict__ wh,
                          f16* __restrict__ wlo, int CO, int CI) {
  int idx = blockIdx.x * 256 + threadIdx.x;  // co*CI + ci
  if (idx >= CO * CI) return;
  int co = idx / CI, ci = idx - co * CI;
#pragma unroll
  for (int t = 0; t < 9; ++t) {
    float v = 256.0f * w[(size_t)idx * 9 + t];
    f16 h = (f16)v;
    size_t o = ((size_t)t * CO + co) * CI + ci;
    wh[o] = h;
    wlo[o] = (f16)(v - (float)h);
  }
}

// ---------------- MFMA dilated 3x3 conv (dbuf implicit GEMM, split fp16) ---
// Double-buffered K-loop over flattened (tap, ci-chunk).  OOB halo lanes DMA
// from the zero page zp (per-lane source address) -> no LDS pre-zeroing.

template <int BM, int BN, bool F32OUT>
__global__ __launch_bounds__(256, 2) void rf_mconv(
    const f16* __restrict__ xh, const f16* __restrict__ xl,
    const f16* __restrict__ wh, const f16* __restrict__ wlo,
    const float* __restrict__ bias, const float* __restrict__ zp,
    f16* __restrict__ oh, f16* __restrict__ ol, float* __restrict__ of,
    int CI, int CO) {
  constexpr int ROWS = BM / 64;
  constexpr int TPI = 4096 / BM;
  constexpr int NSA = BM / 64;
  constexpr int NSB = BN / 64;
  __shared__ f16 sAh[2][BM * 32], sAl[2][BM * 32], sBh[2][BN * 32], sBl[2][BN * 32];
  const int tid = threadIdx.x;
  const int blkpx = blockIdx.x;
  const int cob = blockIdx.y * BN;
  const int b = blkpx / TPI;
  const int h0 = (blkpx - b * TPI) * ROWS;

  const int pA = tid & (BM - 1);
  const int rA = pA >> 6, wpx = pA & 63;
  const int pB = tid & (BN - 1);

  const int wv = tid >> 6, lane = tid & 63;
  const int mrow = lane & 15, quad = lane >> 4;
  const int wm = (BN == 128) ? (wv & 1) * 64 : wv * 64;
  const int wn = (BN == 128) ? (wv >> 1) * 64 : 0;

  f32x4 acc[4][4];
#pragma unroll
  for (int i = 0; i < 4; ++i)
#pragma unroll
    for (int j = 0; j < 4; ++j) acc[i][j] = (f32x4){0.f, 0.f, 0.f, 0.f};

  const int KI = CI >> 5;

  // current-tap staging state
  const f16* cah; const f16* cal; size_t cwb; bool cv;
  auto tapbase = [&](int tt) {
    const int dh = (tt / 3) * 2 - 2, dw = (tt - (tt / 3) * 3) * 2 - 2;
    const int hin = h0 + rA + dh, win = wpx + dw;
    cv = ((unsigned)hin < 64u) && ((unsigned)win < 64u);
    const size_t apix =
        (((size_t)b * 64 + (cv ? hin : 0)) * 64 + (cv ? win : 0)) * CI;
    cah = xh + apix;
    cal = xl + apix;
    cwb = ((size_t)tt * CO + cob + pB) * CI;
  };
  auto stage = [&](int kk, int pb) {
    const int ci0 = kk << 5;
#pragma unroll
    for (int s = 0; s < NSA; ++s) {
      const int cc = ((tid + 256 * s) / BM) & 3;
      const int lb = ((tid & ~63) + 256 * s) * 8;
      const f16* sh_ = cv ? cah + ci0 + cc * 8 : (const f16*)zp;
      const f16* sl_ = cv ? cal + ci0 + cc * 8 : (const f16*)zp;
      async16(sh_, &sAh[pb][lb]);
      async16(sl_, &sAl[pb][lb]);
    }
#pragma unroll
    for (int s = 0; s < NSB; ++s) {
      const int cc = ((tid + 256 * s) / BN) & 3;
      const int lb = ((tid & ~63) + 256 * s) * 8;
      const size_t go = cwb + ci0 + cc * 8;
      async16(wh + go, &sBh[pb][lb]);
      async16(wlo + go, &sBl[pb][lb]);
    }
  };

  tapbase(0);
  stage(0, 0);
  int t = 0, k = 0, p = 0;
  const int total = 9 * KI;
  for (int i = 0; i < total; ++i) {
    __syncthreads();  // drains this wave's DMAs for buf p; guards p^1 reuse
    int kn = k + 1, tn = t;
    if (kn == KI) { kn = 0; tn = t + 1; }
    if (tn < 9) {
      if (tn != t) tapbase(tn);
      stage(kn, p ^ 1);  // in flight during this iteration's MFMA phase
    }
    f16x8 fah[4], fal[4], fbh[4], fbl[4];
#pragma unroll
    for (int mi = 0; mi < 4; ++mi) {
      int ix = (quad * BM + wm + mi * 16 + mrow) * 8;
      fah[mi] = *(const f16x8*)&sAh[p][ix];
      fal[mi] = *(const f16x8*)&sAl[p][ix];
    }
#pragma unroll
    for (int ni = 0; ni < 4; ++ni) {
      int ix = (quad * BN + wn + ni * 16 + mrow) * 8;
      fbh[ni] = *(const f16x8*)&sBh[p][ix];
      fbl[ni] = *(const f16x8*)&sBl[p][ix];
    }
#pragma unroll
    for (int mi = 0; mi < 4; ++mi)
#pragma unroll
      for (int ni = 0; ni < 4; ++ni)
        acc[mi][ni] = __builtin_amdgcn_mfma_f32_16x16x32_f16(fah[mi], fbh[ni], acc[mi][ni], 0, 0, 0);
#pragma unroll
    for (int mi = 0; mi < 4; ++mi)
#pragma unroll
      for (int ni = 0; ni < 4; ++ni)
        acc[mi][ni] = __builtin_amdgcn_mfma_f32_16x16x32_f16(fah[mi], fbl[ni], acc[mi][ni], 0, 0, 0);
#pragma unroll
    for (int mi = 0; mi < 4; ++mi)
#pragma unroll
      for (int ni = 0; ni < 4; ++ni)
        acc[mi][ni] = __builtin_amdgcn_mfma_f32_16x16x32_f16(fal[mi], fbh[ni], acc[mi][ni], 0, 0, 0);
    k = kn; t = tn; p ^= 1;
  }
  const float inv = 1.0f / 4096.0f;
  float bvs[4];
#pragma unroll
  for (int ni = 0; ni < 4; ++ni) bvs[ni] = bias[cob + wn + ni * 16 + mrow];
#pragma unroll
  for (int mi = 0; mi < 4; ++mi) {
#pragma unroll
    for (int rg = 0; rg < 4; ++rg) {
      int px = wm + mi * 16 + quad * 4 + rg;
      int hh = h0 + (px >> 6), wwp = px & 63;
#pragma unroll
      for (int ni = 0; ni < 4; ++ni) {
        int co = cob + wn + ni * 16 + mrow;
        float vv = fmaxf(acc[mi][ni][rg] * inv + bvs[ni], 0.f);
        if (F32OUT) {
          of[(((size_t)b * CO + co) * 64 + hh) * 64 + wwp] = vv;
        } else {
          float sv = vv * 16.f;
          f16 hv = (f16)sv;
          size_t o = (((size_t)b * 64 + hh) * 64 + wwp) * CO + co;
          oh[o] = hv;
          ol[o] = (f16)(sv - (float)hv);
        }
      }
    }
  }
}

// ---------------- scan weight frag prep: w[64][64][9] -> frag order ---------

__global__ void rf_wfrag(const float* __restrict__ w, f16* __restrict__ fh,
                         f16* __restrict__ fl) {
  int gid = blockIdx.x * 256 + threadIdx.x;
  if (gid >= 4608) return;
  int lane = gid & 63;
  int rem = gid >> 6;
  int kc = rem & 1;
  int rem2 = rem >> 1;
  int t = rem2 % 9;
  int w4 = rem2 / 9;
  int co = w4 * 16 + (lane & 15);
  int cib = kc * 32 + (lane >> 4) * 8;
  f16x8 hb, lb;
#pragma unroll
  for (int j = 0; j < 8; ++j) {
    float v = 256.f * w[((size_t)co * 64 + cib + j) * 9 + t];
    f16 h = (f16)v;
    hb[j] = h;
    lb[j] = (f16)(v - (float)h);
  }
  *(f16x8*)&fh[(size_t)gid * 8] = hb;
  *(f16x8*)&fl[(size_t)gid * 8] = lb;
}

// ---------------- MFMA recurrent scan (conv1d k=9 pad 4, 63 steps) ---------

__global__ __launch_bounds__(256, 1) void rf_mscan(
    const float* __restrict__ src, float* __restrict__ dst,
    const f16* __restrict__ fh, const f16* __restrict__ fl,
    const float* __restrict__ bias, int dir) {
  __shared__ f16 ch[72 * 64], cl_[72 * 64];
  const int b = blockIdx.x;
  const int tid = threadIdx.x;
  const int wave = tid >> 6, lane = tid & 63;
  const int quad = lane >> 4, l15 = lane & 15;

  f16x8 Ah[9][2], Al[9][2];
#pragma unroll
  for (int t = 0; t < 9; ++t)
#pragma unroll
    for (int kc = 0; kc < 2; ++kc) {
      int ix = (((wave * 9 + t) * 2 + kc) * 64 + lane) * 8;
      Ah[t][kc] = *(const f16x8*)&fh[ix];
      Al[t][kc] = *(const f16x8*)&fl[ix];
    }
  float bvs[4];
#pragma unroll
  for (int r = 0; r < 4; ++r) bvs[r] = bias[wave * 16 + quad * 4 + r];

  for (int s = tid; s < 2304; s += 256) {
    ((unsigned*)ch)[s] = 0u;
    ((unsigned*)cl_)[s] = 0u;
  }
  __syncthreads();

  const size_t sbase = (size_t)b * 64 * 4096;
  const int row0 = (dir > 0) ? 0 : 63;
  {
    int pos0 = tid & 63, cig = tid >> 6;
#pragma unroll
    for (int q = 0; q < 16; ++q) {
      int ci = cig * 16 + q;
      float v = src[sbase + (size_t)ci * 4096 + row0 * 64 + pos0];
      dst[sbase + (size_t)ci * 4096 + row0 * 64 + pos0] = v;
      f16 h = (f16)v;
      int rowIdx = pos0 + 4;
      int addr = rowIdx * 64 + (((ci >> 3) ^ (rowIdx & 7)) << 3) + (ci & 7);
      ch[addr] = h;
      cl_[addr] = (f16)(v - (float)h);
    }
  }
  __syncthreads();

  const float inv = 1.0f / 256.0f;
  for (int s = 1; s < 64; ++s) {
    const int row = (dir > 0) ? s : 63 - s;
    float srow[4][4];
#pragma unroll
    for (int nt = 0; nt < 4; ++nt)
#pragma unroll
      for (int r = 0; r < 4; ++r)
        srow[nt][r] = src[sbase + (size_t)(wave * 16 + quad * 4 + r) * 4096 +
                          row * 64 + nt * 16 + l15];
    f32x4 acc[4];
#pragma unroll
    for (int nt = 0; nt < 4; ++nt) acc[nt] = (f32x4){0.f, 0.f, 0.f, 0.f};
#pragma unroll
    for (int t = 0; t < 9; ++t)
#pragma unroll
      for (int kc = 0; kc < 2; ++kc) {
#pragma unroll
        for (int nt = 0; nt < 4; ++nt) {
          int rowIdx = nt * 16 + l15 + t;
          int gr = kc * 4 + quad;
          int addr = rowIdx * 64 + ((gr ^ (rowIdx & 7)) << 3);
          f16x8 Bh = *(const f16x8*)&ch[addr];
          f16x8 Bl = *(const f16x8*)&cl_[addr];
          acc[nt] = __builtin_amdgcn_mfma_f32_16x16x32_f16(Ah[t][kc], Bh, acc[nt], 0, 0, 0);
          acc[nt] = __builtin_amdgcn_mfma_f32_16x16x32_f16(Al[t][kc], Bh, acc[nt], 0, 0, 0);
          acc[nt] = __builtin_amdgcn_mfma_f32_16x16x32_f16(Ah[t][kc], Bl, acc[nt], 0, 0, 0);
        }
      }
    __syncthreads();
#pragma unroll
    for (int nt = 0; nt < 4; ++nt) {
      int pos = nt * 16 + l15;
      int rowIdx = pos + 4;
      f16x4 hv, lv;
#pragma unroll
      for (int r = 0; r < 4; ++r) {
        float v = fmaxf(acc[nt][r] * inv + bvs[r], 0.f) + srow[nt][r];
        dst[sbase + (size_t)(wave * 16 + quad * 4 + r) * 4096 + row * 64 + pos] = v;
        f16 h = (f16)v;
        hv[r] = h;
        lv[r] = (f16)(v - (float)h);
      }
      int ci0 = wave * 16 + quad * 4;
      int addr = rowIdx * 64 + (((ci0 >> 3) ^ (rowIdx & 7)) << 3) + (ci0 & 7);
      *(f16x4*)&ch[addr] = hv;
      *(f16x4*)&cl_[addr] = lv;
    }
    __syncthreads();
  }
}

// ---------------- transpose last two dims (64x64) per (b,c) ----------------

__global__ void rf_transpose(const float* __restrict__ src, float* __restrict__ dst) {
  int bc = blockIdx.x;  // 256
  __shared__ float tl[64][65];
  int tid = threadIdx.x;
  const float* sp = src + (size_t)bc * 4096;
  float* dp = dst + (size_t)bc * 4096;
  for (int s = tid; s < 4096; s += 256) {
    int h = s >> 6, w = s & 63;
    tl[w][h] = sp[s];
  }
  __syncthreads();
  for (int s = tid; s < 4096; s += 256) dp[s] = tl[s >> 6][s & 63];
}

// ---------------- final 1x1 conv + relu + 8x8 upsample ----------------

__global__ void rf_final(const float* __restrict__ t, const float* __restrict__ ow,
                         const float* __restrict__ ob, float* __restrict__ out) {
  int b = blockIdx.y;
  int s = blockIdx.x * 256 + threadIdx.x;  // 0..4095
  int w = s >> 6, h = s & 63;
  float acc = ob[0];
  for (int c = 0; c < 64; ++c)
    acc += ow[c] * t[(((size_t)b * 64 + c) * 64 + w) * 64 + h];
  acc = fmaxf(acc, 0.f);
  float4 vv = make_float4(acc, acc, acc, acc);
  for (int dy = 0; dy < 8; ++dy) {
    float* dp = out + ((size_t)b * 512 + h * 8 + dy) * 512 + w * 8;
    *(float4*)dp = vv;
    *(float4*)(dp + 4) = vv;
  }
}

// ---------------- launch ----------------

extern "C" void kernel_launch(void* const* d_in, const int* in_sizes, int n_in,
                              void* d_out, int out_size, void* d_ws, size_t ws_size,
                              hipStream_t stream) {
  const float* in    = (const float*)d_in[0];
  const float* wA    = (const float*)d_in[1];
  const float* bA    = (const float*)d_in[2];
  const float* wB    = (const float*)d_in[3];
  const float* wC    = (const float*)d_in[5];
  const float* bC    = (const float*)d_in[6];
  const float* gamma = (const float*)d_in[7];
  const float* bw1 = (const float*)d_in[8];  const float* bb1 = (const float*)d_in[9];
  const float* bw2 = (const float*)d_in[10]; const float* bb2 = (const float*)d_in[11];
  const float* bw3 = (const float*)d_in[12]; const float* bb3 = (const float*)d_in[13];
  const float* bw4 = (const float*)d_in[14]; const float* bb4 = (const float*)d_in[15];
  const float* bw5 = (const float*)d_in[16]; const float* bb5 = (const float*)d_in[17];
  const float* bw6 = (const float*)d_in[18]; const float* bb6 = (const float*)d_in[19];
  const float* du_w = (const float*)d_in[20]; const float* du_b = (const float*)d_in[21];
  const float* lr_w = (const float*)d_in[22]; const float* lr_b = (const float*)d_in[23];
  const float* ow   = (const float*)d_in[24]; const float* ob   = (const float*)d_in[25];
  float* out = (float*)d_out;
  float* ws = (float*)d_ws;

  // phase-1 buffers
  f16* vH  = (f16*)(ws + 0);
  f16* vL  = (f16*)(ws + 8388608);
  f16* xTh = (f16*)(ws + 16777216);
  f16* wCh = (f16*)(ws + 25165824);
  f16* wCl = (f16*)(ws + 25690112);
  f16* yH  = (f16*)(ws + 16777216);
  f16* yL  = (f16*)(ws + 25165824);
  // conv phase
  f16* w1h = (f16*)(ws + 0);        f16* w1l = (f16*)(ws + 2359296);
  f16* c1H = (f16*)(ws + 4718592);  f16* c1L = (f16*)(ws + 8912896);
  f16* w3h = (f16*)(ws + 13107200); f16* w3l = (f16*)(ws + 14286848);
  f16* w2h = (f16*)(ws + 16777216); f16* w2l = (f16*)(ws + 17956864);
  f16* c2H = (f16*)(ws + 19136512); f16* c2L = (f16*)(ws + 23330816);
  f16* w4h = (f16*)(ws + 27525120); f16* w4l = (f16*)(ws + 28114944);
  f16* c4H = (f16*)(ws + 28704768); f16* c4L = (f16*)(ws + 30801920);
  f16* c3H = c1H;                   f16* c3L = c1L;
  f16* w5h = (f16*)(ws + 0);        f16* w5l = (f16*)(ws + 147456);
  f16* c5H = (f16*)(ws + 294912);   f16* c5L = (f16*)(ws + 1343488);
  f16* w6h = (f16*)(ws + 2392064);  f16* w6l = (f16*)(ws + 2428928);
  float* tin = ws + 4718592;
  float* t0  = ws + 5767168;
  float* t1  = ws + 6815744;
  // scan weight frags (dead c1/c3 zone, after mconv4)
  f16* duFh = (f16*)(ws + 7864320);
  f16* duFl = (f16*)(ws + 7882752);
  f16* lrFh = (f16*)(ws + 7901184);
  f16* lrFl = (f16*)(ws + 7919616);
  float* sm = ws + 33554432;
  float* A_  = sm;
  float* M_  = sm + 16384;
  float* iZ  = sm + 32768;
  float* u_  = sm + 49152;
  float* s_  = sm + 50176;
  float* c0_ = sm + 50304;
  float* fst = sm + 50308;
  float* zp  = sm + 50432;  // 64-float zero page for OOB DMA lanes

  rf_zero<<<1, 64, 0, stream>>>(zp);
  rf_s<<<1, 128, 0, stream>>>(wB, bA, s_, c0_);
  rf_u<<<4, 256, 0, stream>>>(wA, s_, u_);
  rf_fstat<<<4, 256, 0, stream>>>(in, fst);
  rf_A<<<dim3(16, 4), 256, 0, stream>>>(in, u_, c0_, fst, A_, M_);
  rf_Z<<<4096, 256, 0, stream>>>(in, A_, M_, iZ);
  rf_xsplit<<<dim3(64, 16, 4), 256, 0, stream>>>(in, xTh);
  rf_wCsplit<<<512, 256, 0, stream>>>(wC, wCh, wCl);
  rf_vgemmm<<<dim3(32, 8, 4), 256, 0, stream>>>(wCh, wCl, xTh, bC, vH, vL);
  rf_attm<<<dim3(32, 8, 4), 256, 0, stream>>>(vH, vL, A_, M_, iZ, in, gamma, yH, yL);

  rf_wsplit<<<2048, 256, 0, stream>>>(bw1, w1h, w1l, 512, 1024);
  rf_wsplit<<<1024, 256, 0, stream>>>(bw3, w3h, w3l, 512, 512);
  rf_mconv<128, 128, false><<<dim3(128, 4), 256, 0, stream>>>(
      yH, yL, w1h, w1l, bb1, zp, c1H, c1L, nullptr, 1024, 512);
  rf_wsplit<<<1024, 256, 0, stream>>>(bw2, w2h, w2l, 512, 512);
  rf_wsplit<<<512, 256, 0, stream>>>(bw4, w4h, w4l, 256, 512);
  rf_wsplit<<<128, 256, 0, stream>>>(bw5, w5h, w5l, 128, 256);
  rf_wsplit<<<32, 256, 0, stream>>>(bw6, w6h, w6l, 64, 128);
  rf_mconv<128, 128, false><<<dim3(128, 4), 256, 0, stream>>>(
      c1H, c1L, w2h, w2l, bb2, zp, c2H, c2L, nullptr, 512, 512);
  rf_mconv<128, 128, false><<<dim3(128, 4), 256, 0, stream>>>(
      c2H, c2L, w3h, w3l, bb3, zp, c3H, c3L, nullptr, 512, 512);
  rf_mconv<128, 128, false><<<dim3(128, 2), 256, 0, stream>>>(
      c3H, c3L, w4h, w4l, bb4, zp, c4H, c4L, nullptr, 512, 256);
  rf_wfrag<<<18, 256, 0, stream>>>(du_w, duFh, duFl);
  rf_wfrag<<<18, 256, 0, stream>>>(lr_w, lrFh, lrFl);
  rf_mconv<128, 128, false><<<dim3(128, 1), 256, 0, stream>>>(
      c4H, c4L, w5h, w5l, bb5, zp, c5H, c5L, nullptr, 256, 128);
  rf_mconv<256, 64, true><<<dim3(64, 1), 256, 0, stream>>>(
      c5H, c5L, w6h, w6l, bb6, zp, nullptr, nullptr, tin, 128, 64);

  rf_mscan<<<4, 256, 0, stream>>>(tin, t0, duFh, duFl, du_b, +1);
  rf_mscan<<<4, 256, 0, stream>>>(t0, t1, duFh, duFl, du_b, -1);
  rf_transpose<<<256, 256, 0, stream>>>(t1, t0);
  rf_mscan<<<4, 256, 0, stream>>>(t0, t1, lrFh, lrFl, lr_b, +1);
  rf_mscan<<<4, 256, 0, stream>>>(t1, t0, lrFh, lrFl, lr_b, -1);
  rf_final<<<dim3(16, 4), 256, 0, stream>>>(t0, ow, ob, out);
}

// Round 7
// 1978.664 us; speedup vs baseline: 1.8563x; 1.8563x over previous
//
#include <hip/hip_runtime.h>

// resFAN round 7: single-fp16 everywhere (no hi/lo split).  Post-mortem of
// r6 showed conv is LDS-pipe-bound (128KB frag reads/CU-iter vs 460cyc MFMA);
// threshold is 2% of max|ref| -> split precision machinery (2x LDS, 3x MFMA)
// is unnecessary.  Convs now BK=64 dbuf single-stream; vgemm/att/scan 1-pass.
//
// Error budget: fp16 quant 2^-11 per tensor, no amplification (weights std
// 0.01), gamma=0.1 damps attention branch -> final abs err ~1e-5 vs 8e-5 thr.

#define NPIX 4096

typedef _Float16 f16;
typedef _Float16 f16x8 __attribute__((ext_vector_type(8)));
typedef _Float16 f16x4 __attribute__((ext_vector_type(4)));
typedef float f32x4 __attribute__((ext_vector_type(4)));

__device__ inline void async16(const void* g, void* l) {
  __builtin_amdgcn_global_load_lds(
      (const __attribute__((address_space(1))) unsigned int*)g,
      (__attribute__((address_space(3))) unsigned int*)l, 16, 0, 0);
}

// ---------------- small prep kernels ----------------

__global__ void rf_zero(float* __restrict__ z) { z[threadIdx.x] = 0.f; }

__global__ void rf_s(const float* __restrict__ wB, const float* __restrict__ bA,
                     float* __restrict__ s_out, float* __restrict__ c0_out) {
  int c = threadIdx.x;  // 128 threads
  const float* row = wB + (size_t)c * 1024;
  float acc = 0.f;
  for (int i = 0; i < 1024; ++i) acc += row[i];
  s_out[c] = acc;
  __shared__ float sh[128];
  sh[c] = acc * bA[c];
  __syncthreads();
  for (int off = 64; off > 0; off >>= 1) {
    if (c < off) sh[c] += sh[c + off];
    __syncthreads();
  }
  if (c == 0) c0_out[0] = sh[0];
}

__global__ void rf_u(const float* __restrict__ wA, const float* __restrict__ s,
                     float* __restrict__ u) {
  int i = blockIdx.x * 256 + threadIdx.x;  // 1024 total
  float acc = 0.f;
  for (int c = 0; c < 128; ++c) acc += s[c] * wA[(size_t)c * 1024 + i];
  u[i] = acc;
}

__global__ void rf_fstat(const float* __restrict__ in, float* __restrict__ fstat) {
  int b = blockIdx.x;
  int t = threadIdx.x;
  const float* f = in + ((size_t)b * 1025 + 1024) * NPIX;
  float mx = -1e30f, mn = 1e30f;
  for (int j = t; j < NPIX; j += 256) {
    float v = f[j];
    mx = fmaxf(mx, v);
    mn = fminf(mn, v);
  }
  __shared__ float smx[256], smn[256];
  smx[t] = mx; smn[t] = mn;
  __syncthreads();
  for (int off = 128; off > 0; off >>= 1) {
    if (t < off) {
      smx[t] = fmaxf(smx[t], smx[t + off]);
      smn[t] = fminf(smn[t], smn[t + off]);
    }
    __syncthreads();
  }
  if (t == 0) { fstat[b] = smx[0]; fstat[4 + b] = smn[0]; }
}

__global__ __launch_bounds__(256) void rf_A(const float* __restrict__ in,
                                            const float* __restrict__ u,
                                            const float* __restrict__ c0p,
                                            const float* __restrict__ fst,
                                            float* __restrict__ A, float* __restrict__ M) {
  __shared__ float ul[1024];
  int b = blockIdx.y;
  int n = blockIdx.x * 256 + threadIdx.x;
  for (int s = threadIdx.x; s < 1024; s += 256) ul[s] = u[s];
  __syncthreads();
  const float* xp = in + (size_t)b * 1025 * NPIX + n;
  float acc = c0p[0];
#pragma unroll 8
  for (int i = 0; i < 1024; ++i) acc = fmaf(ul[i], xp[(size_t)i * NPIX], acc);
  A[b * NPIX + n] = acc;
  M[b * NPIX + n] = fmaxf(acc * fst[b], acc * fst[4 + b]);
}

__global__ void rf_Z(const float* __restrict__ in, const float* __restrict__ A,
                     const float* __restrict__ M, float* __restrict__ iZ) {
  int idx = blockIdx.x * 4 + (threadIdx.x >> 6);  // (b,n) pair, 16384 total
  int lane = threadIdx.x & 63;
  int b = idx >> 12;
  const float* f = in + ((size_t)b * 1025 + 1024) * NPIX;
  float a = A[idx], m = M[idx];
  float acc = 0.f;
#pragma unroll 4
  for (int it = 0; it < 64; ++it) acc += __expf(a * f[lane + it * 64] - m);
  for (int off = 32; off > 0; off >>= 1) acc += __shfl_down(acc, off, 64);
  if (lane == 0) iZ[idx] = 1.0f / acc;
}

// ---------------- x transpose: [b][ci][n] f32 -> [b][n][ci] f16, scale 16 ---

__global__ void rf_xsplit(const float* __restrict__ in, f16* __restrict__ xh) {
  __shared__ float tl[64][65];
  int nt = blockIdx.x, ct = blockIdx.y, b = blockIdx.z;
  int n0 = nt * 64, c0 = ct * 64;
  int tid = threadIdx.x;
  for (int s = tid; s < 4096; s += 256) {
    int r = s >> 6, c = s & 63;
    tl[r][c] = in[((size_t)b * 1025 + c0 + r) * NPIX + n0 + c];
  }
  __syncthreads();
  for (int s = tid; s < 512; s += 256) {
    int n = s >> 3, g = s & 7;
    f16x8 hb;
#pragma unroll
    for (int q = 0; q < 8; ++q) hb[q] = (f16)(16.f * tl[g * 8 + q][n]);
    size_t o = ((size_t)b * NPIX + n0 + n) * 1024 + c0 + g * 8;
    *(f16x8*)&xh[o] = hb;
  }
}

// ---------------- wC cast: [1024][1024] f32 -> f16, scale 256 --------------

__global__ void rf_wC1(const float* __restrict__ wC, f16* __restrict__ wh) {
  int base = (blockIdx.x * 256 + threadIdx.x) * 8;
  f16x8 hb;
#pragma unroll
  for (int q = 0; q < 8; ++q) hb[q] = (f16)(256.f * wC[base + q]);
  *(f16x8*)&wh[base] = hb;
}

// ---------------- MFMA v-GEMM (dbuf, single fp16): v = wC @ x + bC --------

__global__ __launch_bounds__(256, 2) void rf_vgemmm(
    const f16* __restrict__ wh, const f16* __restrict__ xh,
    const float* __restrict__ bC, f16* __restrict__ vH) {
  __shared__ f16 sA[2][4096], sB[2][4096];
  const int tid = threadIdx.x;
  const int nb = blockIdx.x * 128, cb = blockIdx.y * 128, b = blockIdx.z;
  const int pA = tid & 127;
  const int wv = tid >> 6, lane = tid & 63;
  const int mrow = lane & 15, quad = lane >> 4;
  const int wm = (wv & 1) * 64, wn = (wv >> 1) * 64;
  const size_t abase = (size_t)(cb + pA) * 1024;
  const size_t bbase = ((size_t)b * NPIX + nb + pA) * 1024;
  f32x4 acc[4][4];
#pragma unroll
  for (int i = 0; i < 4; ++i)
#pragma unroll
    for (int j = 0; j < 4; ++j) acc[i][j] = (f32x4){0.f, 0.f, 0.f, 0.f};

  auto stage = [&](int k0, int pb) {
#pragma unroll
    for (int s = 0; s < 2; ++s) {
      const int cc = ((tid + 256 * s) >> 7) & 3;
      const int lb = ((tid & ~63) + 256 * s) * 8;
      async16(wh + abase + k0 + cc * 8, &sA[pb][lb]);
      async16(xh + bbase + k0 + cc * 8, &sB[pb][lb]);
    }
  };
  stage(0, 0);
  int p = 0;
  for (int k0 = 0; k0 < 1024; k0 += 32) {
    __syncthreads();
    if (k0 + 32 < 1024) stage(k0 + 32, p ^ 1);
    f16x8 fa[4], fb[4];
#pragma unroll
    for (int mi = 0; mi < 4; ++mi)
      fa[mi] = *(const f16x8*)&sA[p][(quad * 128 + wm + mi * 16 + mrow) * 8];
#pragma unroll
    for (int ni = 0; ni < 4; ++ni)
      fb[ni] = *(const f16x8*)&sB[p][(quad * 128 + wn + ni * 16 + mrow) * 8];
#pragma unroll
    for (int mi = 0; mi < 4; ++mi)
#pragma unroll
      for (int ni = 0; ni < 4; ++ni)
        acc[mi][ni] = __builtin_amdgcn_mfma_f32_16x16x32_f16(fa[mi], fb[ni], acc[mi][ni], 0, 0, 0);
    p ^= 1;
  }
  const float inv = 1.0f / 4096.0f;
#pragma unroll
  for (int mi = 0; mi < 4; ++mi) {
#pragma unroll
    for (int rg = 0; rg < 4; ++rg) {
      int c = cb + wm + mi * 16 + quad * 4 + rg;
      float bv = bC[c];
#pragma unroll
      for (int ni = 0; ni < 4; ++ni) {
        int j = nb + wn + ni * 16 + mrow;
        vH[((size_t)b * 1024 + c) * NPIX + j] =
            (f16)(16.f * (acc[mi][ni][rg] * inv + bv));
      }
    }
  }
}

// ---------------- MFMA attention out-GEMM (single fp16) -> y ---------------

__global__ __launch_bounds__(256, 2) void rf_attm(
    const f16* __restrict__ vH,
    const float* __restrict__ Aarr, const float* __restrict__ Marr,
    const float* __restrict__ iZ, const float* __restrict__ in,
    const float* __restrict__ gptr, f16* __restrict__ yH) {
  __shared__ f16 sAh[4096], sPh[4096];
  const int tid = threadIdx.x;
  const int ib = blockIdx.x * 128, cb = blockIdx.y * 128, b = blockIdx.z;
  const int pA = tid & 127;
  const int wv = tid >> 6, lane = tid & 63;
  const int mrow = lane & 15, quad = lane >> 4;
  const int wm = (wv & 1) * 64, wn = (wv >> 1) * 64;
  const size_t vbase = ((size_t)b * 1024 + cb + pA) * NPIX;
  const int ni_ = tid & 127;
  const int kc0 = tid >> 7;  // 0..1
  const float av = Aarr[b * NPIX + ib + ni_];
  const float mv = Marr[b * NPIX + ib + ni_];
  const float zv = iZ[b * NPIX + ib + ni_] * 16.f;
  const float* f = in + ((size_t)b * 1025 + 1024) * NPIX;
  f32x4 acc[4][4];
#pragma unroll
  for (int i = 0; i < 4; ++i)
#pragma unroll
    for (int j = 0; j < 4; ++j) acc[i][j] = (f32x4){0.f, 0.f, 0.f, 0.f};
  for (int j0 = 0; j0 < NPIX; j0 += 32) {
#pragma unroll
    for (int s = 0; s < 2; ++s) {
      const int cc = ((tid + 256 * s) >> 7) & 3;
      const int lb = ((tid & ~63) + 256 * s) * 8;
      async16(vH + vbase + j0 + cc * 8, &sAh[lb]);
    }
#pragma unroll
    for (int it = 0; it < 2; ++it) {
      const int kc = kc0 + 2 * it;
      const float4 fa = *(const float4*)&f[j0 + kc * 8];
      const float4 fb = *(const float4*)&f[j0 + kc * 8 + 4];
      const float fj[8] = {fa.x, fa.y, fa.z, fa.w, fb.x, fb.y, fb.z, fb.w};
      f16x8 ph;
#pragma unroll
      for (int q = 0; q < 8; ++q)
        ph[q] = (f16)(__expf(fmaf(av, fj[q], -mv)) * zv);
      *(f16x8*)&sPh[(kc * 128 + ni_) * 8] = ph;
    }
    __syncthreads();
    f16x8 fa[4], fb[4];
#pragma unroll
    for (int mi = 0; mi < 4; ++mi)
      fa[mi] = *(const f16x8*)&sAh[(quad * 128 + wm + mi * 16 + mrow) * 8];
#pragma unroll
    for (int ni = 0; ni < 4; ++ni)
      fb[ni] = *(const f16x8*)&sPh[(quad * 128 + wn + ni * 16 + mrow) * 8];
#pragma unroll
    for (int mi = 0; mi < 4; ++mi)
#pragma unroll
      for (int ni = 0; ni < 4; ++ni)
        acc[mi][ni] = __builtin_amdgcn_mfma_f32_16x16x32_f16(fa[mi], fb[ni], acc[mi][ni], 0, 0, 0);
    __syncthreads();
  }
  const float g = gptr[0];
  const float inv = 1.0f / 256.0f;
#pragma unroll
  for (int mi = 0; mi < 4; ++mi) {
    const int cbase = cb + wm + mi * 16 + quad * 4;
#pragma unroll
    for (int ni = 0; ni < 4; ++ni) {
      const int i = ib + wn + ni * 16 + mrow;
      f16x4 hv;
#pragma unroll
      for (int rg = 0; rg < 4; ++rg) {
        float xr = in[((size_t)b * 1025 + cbase + rg) * NPIX + i];
        hv[rg] = (f16)(16.f * (g * (acc[mi][ni][rg] * inv) + xr));
      }
      *(f16x4*)&yH[((size_t)b * NPIX + i) * 1024 + cbase] = hv;
    }
  }
}

// ---------------- weight cast prep: [CO][CI][3][3] -> [9][CO][CI] f16 ------

__global__ void rf_wsingle(const float* __restrict__ w, f16* __restrict__ wh,
                           int CO, int CI) {
  int idx = blockIdx.x * 256 + threadIdx.x;  // co*CI + ci
  if (idx >= CO * CI) return;
  int co = idx / CI, ci = idx - co * CI;
#pragma unroll
  for (int t = 0; t < 9; ++t)
    wh[((size_t)t * CO + co) * CI + ci] = (f16)(256.0f * w[(size_t)idx * 9 + t]);
}

// ---------------- MFMA dilated 3x3 conv (dbuf, BK=64, single fp16) ---------

template <int BM, int BN, bool F32OUT>
__global__ __launch_bounds__(256, 2) void rf_mconv(
    const f16* __restrict__ xh, const f16* __restrict__ wh,
    const float* __restrict__ bias, const float* __restrict__ zp,
    f16* __restrict__ oh, float* __restrict__ of, int CI, int CO) {
  constexpr int ROWS = BM / 64;
  constexpr int TPI = 4096 / BM;
  constexpr int NSA = BM / 32;
  constexpr int NSB = BN / 32;
  __shared__ f16 sA[2][BM * 64], sB[2][BN * 64];
  const int tid = threadIdx.x;
  const int blkpx = blockIdx.x;
  const int cob = blockIdx.y * BN;
  const int b = blkpx / TPI;
  const int h0 = (blkpx - b * TPI) * ROWS;

  const int pA = tid & (BM - 1);
  const int rA = pA >> 6, wpx = pA & 63;
  const int pB = tid & (BN - 1);

  const int wv = tid >> 6, lane = tid & 63;
  const int mrow = lane & 15, quad = lane >> 4;
  const int wm = (BN == 128) ? (wv & 1) * 64 : wv * 64;
  const int wn = (BN == 128) ? (wv >> 1) * 64 : 0;

  f32x4 acc[4][4];
#pragma unroll
  for (int i = 0; i < 4; ++i)
#pragma unroll
    for (int j = 0; j < 4; ++j) acc[i][j] = (f32x4){0.f, 0.f, 0.f, 0.f};

  const int KI = CI >> 6;

  const f16* cah; size_t cwb; bool cv;
  auto tapbase = [&](int tt) {
    const int dh = (tt / 3) * 2 - 2, dw = (tt - (tt / 3) * 3) * 2 - 2;
    const int hin = h0 + rA + dh, win = wpx + dw;
    cv = ((unsigned)hin < 64u) && ((unsigned)win < 64u);
    cah = xh + (((size_t)b * 64 + (cv ? hin : 0)) * 64 + (cv ? win : 0)) * CI;
    cwb = ((size_t)tt * CO + cob + pB) * CI;
  };
  auto stage = [&](int kk, int pb) {
    const int ci0 = kk << 6;
#pragma unroll
    for (int s = 0; s < NSA; ++s) {
      const int cc = ((tid + 256 * s) / BM) & 7;
      const int lb = ((tid & ~63) + 256 * s) * 8;
      const f16* sp = cv ? cah + ci0 + cc * 8 : (const f16*)zp;
      async16(sp, &sA[pb][lb]);
    }
#pragma unroll
    for (int s = 0; s < NSB; ++s) {
      const int cc = ((tid + 256 * s) / BN) & 7;
      const int lb = ((tid & ~63) + 256 * s) * 8;
      async16(wh + cwb + ci0 + cc * 8, &sB[pb][lb]);
    }
  };

  tapbase(0);
  stage(0, 0);
  int t = 0, k = 0, p = 0;
  const int total = 9 * KI;
  for (int i = 0; i < total; ++i) {
    __syncthreads();
    int kn = k + 1, tn = t;
    if (kn == KI) { kn = 0; tn = t + 1; }
    if (tn < 9) {
      if (tn != t) tapbase(tn);
      stage(kn, p ^ 1);
    }
#pragma unroll
    for (int kc = 0; kc < 2; ++kc) {
      f16x8 fa[4], fb[4];
#pragma unroll
      for (int mi = 0; mi < 4; ++mi)
        fa[mi] = *(const f16x8*)&sA[p][((kc * 4 + quad) * BM + wm + mi * 16 + mrow) * 8];
#pragma unroll
      for (int ni = 0; ni < 4; ++ni)
        fb[ni] = *(const f16x8*)&sB[p][((kc * 4 + quad) * BN + wn + ni * 16 + mrow) * 8];
#pragma unroll
      for (int mi = 0; mi < 4; ++mi)
#pragma unroll
        for (int ni = 0; ni < 4; ++ni)
          acc[mi][ni] = __builtin_amdgcn_mfma_f32_16x16x32_f16(fa[mi], fb[ni], acc[mi][ni], 0, 0, 0);
    }
    k = kn; t = tn; p ^= 1;
  }
  const float inv = 1.0f / 4096.0f;
  float bvs[4];
#pragma unroll
  for (int ni = 0; ni < 4; ++ni) bvs[ni] = bias[cob + wn + ni * 16 + mrow];
#pragma unroll
  for (int mi = 0; mi < 4; ++mi) {
#pragma unroll
    for (int rg = 0; rg < 4; ++rg) {
      int px = wm + mi * 16 + quad * 4 + rg;
      int hh = h0 + (px >> 6), wwp = px & 63;
#pragma unroll
      for (int ni = 0; ni < 4; ++ni) {
        int co = cob + wn + ni * 16 + mrow;
        float vv = fmaxf(acc[mi][ni][rg] * inv + bvs[ni], 0.f);
        if (F32OUT) {
          of[(((size_t)b * CO + co) * 64 + hh) * 64 + wwp] = vv;
        } else {
          oh[(((size_t)b * 64 + hh) * 64 + wwp) * CO + co] = (f16)(vv * 16.f);
        }
      }
    }
  }
}

// ---------------- scan weight frag prep: w[64][64][9] -> frag order ---------

__global__ void rf_wfrag(const float* __restrict__ w, f16* __restrict__ fh) {
  int gid = blockIdx.x * 256 + threadIdx.x;
  if (gid >= 4608) return;
  int lane = gid & 63;
  int rem = gid >> 6;
  int kc = rem & 1;
  int rem2 = rem >> 1;
  int t = rem2 % 9;
  int w4 = rem2 / 9;
  int co = w4 * 16 + (lane & 15);
  int cib = kc * 32 + (lane >> 4) * 8;
  f16x8 hb;
#pragma unroll
  for (int j = 0; j < 8; ++j)
    hb[j] = (f16)(256.f * w[((size_t)co * 64 + cib + j) * 9 + t]);
  *(f16x8*)&fh[(size_t)gid * 8] = hb;
}

// ---------------- MFMA recurrent scan (single fp16 carry) ------------------

__global__ __launch_bounds__(256, 1) void rf_mscan(
    const float* __restrict__ src, float* __restrict__ dst,
    const f16* __restrict__ fh, const float* __restrict__ bias, int dir) {
  __shared__ f16 ch[72 * 64];
  const int b = blockIdx.x;
  const int tid = threadIdx.x;
  const int wave = tid >> 6, lane = tid & 63;
  const int quad = lane >> 4, l15 = lane & 15;

  f16x8 Ah[9][2];
#pragma unroll
  for (int t = 0; t < 9; ++t)
#pragma unroll
    for (int kc = 0; kc < 2; ++kc)
      Ah[t][kc] = *(const f16x8*)&fh[(((wave * 9 + t) * 2 + kc) * 64 + lane) * 8];
  float bvs[4];
#pragma unroll
  for (int r = 0; r < 4; ++r) bvs[r] = bias[wave * 16 + quad * 4 + r];

  for (int s = tid; s < 2304; s += 256) ((unsigned*)ch)[s] = 0u;
  __syncthreads();

  const size_t sbase = (size_t)b * 64 * 4096;
  const int row0 = (dir > 0) ? 0 : 63;
  {
    int pos0 = tid & 63, cig = tid >> 6;
#pragma unroll
    for (int q = 0; q < 16; ++q) {
      int ci = cig * 16 + q;
      float v = src[sbase + (size_t)ci * 4096 + row0 * 64 + pos0];
      dst[sbase + (size_t)ci * 4096 + row0 * 64 + pos0] = v;
      int rowIdx = pos0 + 4;
      ch[rowIdx * 64 + (((ci >> 3) ^ (rowIdx & 7)) << 3) + (ci & 7)] = (f16)v;
    }
  }
  __syncthreads();

  const float inv = 1.0f / 256.0f;
  for (int s = 1; s < 64; ++s) {
    const int row = (dir > 0) ? s : 63 - s;
    float srow[4][4];
#pragma unroll
    for (int nt = 0; nt < 4; ++nt)
#pragma unroll
      for (int r = 0; r < 4; ++r)
        srow[nt][r] = src[sbase + (size_t)(wave * 16 + quad * 4 + r) * 4096 +
                          row * 64 + nt * 16 + l15];
    f32x4 acc[4];
#pragma unroll
    for (int nt = 0; nt < 4; ++nt) acc[nt] = (f32x4){0.f, 0.f, 0.f, 0.f};
#pragma unroll
    for (int t = 0; t < 9; ++t)
#pragma unroll
      for (int kc = 0; kc < 2; ++kc) {
#pragma unroll
        for (int nt = 0; nt < 4; ++nt) {
          int rowIdx = nt * 16 + l15 + t;
          int gr = kc * 4 + quad;
          f16x8 Bh = *(const f16x8*)&ch[rowIdx * 64 + ((gr ^ (rowIdx & 7)) << 3)];
          acc[nt] = __builtin_amdgcn_mfma_f32_16x16x32_f16(Ah[t][kc], Bh, acc[nt], 0, 0, 0);
        }
      }
    __syncthreads();
#pragma unroll
    for (int nt = 0; nt < 4; ++nt) {
      int pos = nt * 16 + l15;
      int rowIdx = pos + 4;
      f16x4 hv;
#pragma unroll
      for (int r = 0; r < 4; ++r) {
        float v = fmaxf(acc[nt][r] * inv + bvs[r], 0.f) + srow[nt][r];
        dst[sbase + (size_t)(wave * 16 + quad * 4 + r) * 4096 + row * 64 + pos] = v;
        hv[r] = (f16)v;
      }
      int ci0 = wave * 16 + quad * 4;
      *(f16x4*)&ch[rowIdx * 64 + (((ci0 >> 3) ^ (rowIdx & 7)) << 3) + (ci0 & 7)] = hv;
    }
    __syncthreads();
  }
}

// ---------------- transpose last two dims (64x64) per (b,c) ----------------

__global__ void rf_transpose(const float* __restrict__ src, float* __restrict__ dst) {
  int bc = blockIdx.x;  // 256
  __shared__ float tl[64][65];
  int tid = threadIdx.x;
  const float* sp = src + (size_t)bc * 4096;
  float* dp = dst + (size_t)bc * 4096;
  for (int s = tid; s < 4096; s += 256) {
    int h = s >> 6, w = s & 63;
    tl[w][h] = sp[s];
  }
  __syncthreads();
  for (int s = tid; s < 4096; s += 256) dp[s] = tl[s >> 6][s & 63];
}

// ---------------- final 1x1 conv + relu + 8x8 upsample ----------------

__global__ void rf_final(const float* __restrict__ t, const float* __restrict__ ow,
                         const float* __restrict__ ob, float* __restrict__ out) {
  int b = blockIdx.y;
  int s = blockIdx.x * 256 + threadIdx.x;  // 0..4095
  int w = s >> 6, h = s & 63;
  float acc = ob[0];
  for (int c = 0; c < 64; ++c)
    acc += ow[c] * t[(((size_t)b * 64 + c) * 64 + w) * 64 + h];
  acc = fmaxf(acc, 0.f);
  float4 vv = make_float4(acc, acc, acc, acc);
  for (int dy = 0; dy < 8; ++dy) {
    float* dp = out + ((size_t)b * 512 + h * 8 + dy) * 512 + w * 8;
    *(float4*)dp = vv;
    *(float4*)(dp + 4) = vv;
  }
}

// ---------------- launch ----------------

extern "C" void kernel_launch(void* const* d_in, const int* in_sizes, int n_in,
                              void* d_out, int out_size, void* d_ws, size_t ws_size,
                              hipStream_t stream) {
  const float* in    = (const float*)d_in[0];
  const float* wA    = (const float*)d_in[1];
  const float* bA    = (const float*)d_in[2];
  const float* wB    = (const float*)d_in[3];
  const float* wC    = (const float*)d_in[5];
  const float* bC    = (const float*)d_in[6];
  const float* gamma = (const float*)d_in[7];
  const float* bw1 = (const float*)d_in[8];  const float* bb1 = (const float*)d_in[9];
  const float* bw2 = (const float*)d_in[10]; const float* bb2 = (const float*)d_in[11];
  const float* bw3 = (const float*)d_in[12]; const float* bb3 = (const float*)d_in[13];
  const float* bw4 = (const float*)d_in[14]; const float* bb4 = (const float*)d_in[15];
  const float* bw5 = (const float*)d_in[16]; const float* bb5 = (const float*)d_in[17];
  const float* bw6 = (const float*)d_in[18]; const float* bb6 = (const float*)d_in[19];
  const float* du_w = (const float*)d_in[20]; const float* du_b = (const float*)d_in[21];
  const float* lr_w = (const float*)d_in[22]; const float* lr_b = (const float*)d_in[23];
  const float* ow   = (const float*)d_in[24]; const float* ob   = (const float*)d_in[25];
  float* out = (float*)d_out;
  float* ws = (float*)d_ws;

  // phase-1 (attention) buffers; offsets in f32 slots (f16 elems = 2x)
  f16* vH  = (f16*)(ws + 0);          // 16.8M f16 -> [0, 4194304)
  f16* xTh = (f16*)(ws + 4194304);    // [4194304, 8388608)
  f16* wCh = (f16*)(ws + 8388608);    // [8388608, 8912896)
  f16* yH  = (f16*)(ws + 16777216);   // [16777216, 20971520)
  // conv phase
  f16* w1h = (f16*)(ws + 0);          // [0, 2359296)
  f16* c1H = (f16*)(ws + 2359296);    // [2359296, 6553600)
  f16* w3h = (f16*)(ws + 6553600);    // [6553600, 7733248)
  f16* w2h = (f16*)(ws + 16777216);   // [16777216, 17956864)  (yH dead)
  f16* c2H = (f16*)(ws + 17956864);   // [17956864, 22151168)
  f16* w4h = (f16*)(ws + 22151168);   // [22151168, 22740992)
  f16* c4H = (f16*)(ws + 22740992);   // [22740992, 24838144)
  f16* c3H = c1H;
  f16* w5h = (f16*)(ws + 0);          // [0, 147456)       (w1 dead)
  f16* c5H = (f16*)(ws + 147456);     // [147456, 1196032)
  f16* w6h = (f16*)(ws + 1196032);    // [1196032, 1232896)
  float* tin = ws + 1232896;          // [1232896, 2281472)
  float* t0  = ws + 2281472;          // [2281472, 3330048)
  float* t1  = ws + 3330048;          // [3330048, 4378624)
  f16* duFh = (f16*)(ws + 4378624);   // [4378624, 4397056)  (c1/c3 dead)
  f16* lrFh = (f16*)(ws + 4397056);   // [4397056, 4415488)
  float* sm = ws + 33554432;
  float* A_  = sm;
  float* M_  = sm + 16384;
  float* iZ  = sm + 32768;
  float* u_  = sm + 49152;
  float* s_  = sm + 50176;
  float* c0_ = sm + 50304;
  float* fst = sm + 50308;
  float* zp  = sm + 50432;  // 64-float zero page for OOB DMA lanes

  rf_zero<<<1, 64, 0, stream>>>(zp);
  rf_s<<<1, 128, 0, stream>>>(wB, bA, s_, c0_);
  rf_u<<<4, 256, 0, stream>>>(wA, s_, u_);
  rf_fstat<<<4, 256, 0, stream>>>(in, fst);
  rf_A<<<dim3(16, 4), 256, 0, stream>>>(in, u_, c0_, fst, A_, M_);
  rf_Z<<<4096, 256, 0, stream>>>(in, A_, M_, iZ);
  rf_xsplit<<<dim3(64, 16, 4), 256, 0, stream>>>(in, xTh);
  rf_wC1<<<512, 256, 0, stream>>>(wC, wCh);
  rf_vgemmm<<<dim3(32, 8, 4), 256, 0, stream>>>(wCh, xTh, bC, vH);
  rf_attm<<<dim3(32, 8, 4), 256, 0, stream>>>(vH, A_, M_, iZ, in, gamma, yH);

  rf_wsingle<<<2048, 256, 0, stream>>>(bw1, w1h, 512, 1024);
  rf_wsingle<<<1024, 256, 0, stream>>>(bw3, w3h, 512, 512);
  rf_mconv<128, 128, false><<<dim3(128, 4), 256, 0, stream>>>(
      yH, w1h, bb1, zp, c1H, nullptr, 1024, 512);
  rf_wsingle<<<1024, 256, 0, stream>>>(bw2, w2h, 512, 512);
  rf_wsingle<<<512, 256, 0, stream>>>(bw4, w4h, 256, 512);
  rf_wsingle<<<128, 256, 0, stream>>>(bw5, w5h, 128, 256);
  rf_wsingle<<<32, 256, 0, stream>>>(bw6, w6h, 64, 128);
  rf_mconv<128, 128, false><<<dim3(128, 4), 256, 0, stream>>>(
      c1H, w2h, bb2, zp, c2H, nullptr, 512, 512);
  rf_mconv<128, 128, false><<<dim3(128, 4), 256, 0, stream>>>(
      c2H, w3h, bb3, zp, c3H, nullptr, 512, 512);
  rf_mconv<128, 128, false><<<dim3(128, 2), 256, 0, stream>>>(
      c3H, w4h, bb4, zp, c4H, nullptr, 512, 256);
  rf_wfrag<<<18, 256, 0, stream>>>(du_w, duFh);
  rf_wfrag<<<18, 256, 0, stream>>>(lr_w, lrFh);
  rf_mconv<128, 128, false><<<dim3(128, 1), 256, 0, stream>>>(
      c4H, w5h, bb5, zp, c5H, nullptr, 256, 128);
  rf_mconv<256, 64, true><<<dim3(64, 1), 256, 0, stream>>>(
      c5H, w6h, bb6, zp, nullptr, tin, 128, 64);

  rf_mscan<<<4, 256, 0, stream>>>(tin, t0, duFh, du_b, +1);
  rf_mscan<<<4, 256, 0, stream>>>(t0, t1, duFh, du_b, -1);
  rf_transpose<<<256, 256, 0, stream>>>(t1, t0);
  rf_mscan<<<4, 256, 0, stream>>>(t0, t1, lrFh, lr_b, +1);
  rf_mscan<<<4, 256, 0, stream>>>(t1, t0, lrFh, lr_b, -1);
  rf_final<<<dim3(16, 4), 256, 0, stream>>>(t0, ow, ob, out);
}